// Round 12
// baseline (54.387 us; speedup 1.0000x reference)
//
#include <hip/hip_runtime.h>
#include <math.h>

// Problem constants (from reference setup_inputs)
constexpr int B  = 2;
constexpr int Lq = 4096;
constexpr int Lk = 4096;
constexpr int H  = 8;
constexpr int C  = 64;
constexpr int K  = 32;
constexpr float INV_SCALE = 0.125f;
constexpr int HC = H * C;                 // 512 elements: row stride in key/value
constexpr int NKV = B * Lk * H * C;       // 4,194,304 elements per array

typedef _Float16 h2 __attribute__((ext_vector_type(2)));
typedef _Float16 half4_t __attribute__((ext_vector_type(4)));

static __device__ __forceinline__ h2 pack_h2(float lo, float hi) {
    return __builtin_bit_cast(h2, __builtin_amdgcn_cvt_pkrtz(lo, hi));
}

#if __has_builtin(__builtin_amdgcn_fdot2)
static __device__ __forceinline__ float fdot2(h2 a, h2 b, float c) {
    return __builtin_amdgcn_fdot2(a, b, c, false);
}
#else
static __device__ __forceinline__ float fdot2(h2 a, h2 b, float c) {
    return c + (float)a.x * (float)b.x + (float)a.y * (float)b.y;
}
#endif

static __device__ __forceinline__ h2 shfl_h2_xor(h2 v, int m) {
    int i = __builtin_bit_cast(int, v);
    i = __shfl_xor(i, m);
    return __builtin_bit_cast(h2, i);
}

// ---- DPP cross-lane (VALU pipe, not DS) ----
template<int CTRL>
static __device__ __forceinline__ float dpp_f(float x) {
    return __builtin_bit_cast(float,
        __builtin_amdgcn_update_dpp(0, __builtin_bit_cast(int, x),
                                    CTRL, 0xF, 0xF, true));
}
template<int CTRL>
static __device__ __forceinline__ h2 dpp_h2(h2 x) {
    return __builtin_bit_cast(h2,
        __builtin_amdgcn_update_dpp(0, __builtin_bit_cast(int, x),
                                    CTRL, 0xF, 0xF, true));
}

// async global->LDS, 16 B per lane. LDS dest = wave-uniform base + lane*16;
// global SOURCE is per-lane (m173) -> a single instruction gathers 8
// different 128-B rows (8 lanes each, consecutive 16-B chunks).
static __device__ __forceinline__ void stage16(const void* g, void* l) {
    __builtin_amdgcn_global_load_lds(
        (const __attribute__((address_space(1))) void*)g,
        (__attribute__((address_space(3))) void*)l,
        16, 0, 0);
}

// ---------------- prepass: fp32 K,V -> fp16 in d_ws (streamed) ----------------
__global__ __launch_bounds__(256) void convert_kv_f16(
    const float* __restrict__ key,
    const float* __restrict__ value,
    _Float16*    __restrict__ kh,
    _Float16*    __restrict__ vh)
{
    const int n4 = NKV / 4;               // float4 chunks per array
    for (int i = blockIdx.x * blockDim.x + threadIdx.x;
         i < 2 * n4; i += gridDim.x * blockDim.x) {
        if (i < n4) {
            const float4 v = ((const float4*)key)[i];
            half4_t h = { (_Float16)v.x, (_Float16)v.y, (_Float16)v.z, (_Float16)v.w };
            ((half4_t*)kh)[i] = h;
        } else {
            const float4 v = ((const float4*)value)[i - n4];
            half4_t h = { (_Float16)v.x, (_Float16)v.y, (_Float16)v.z, (_Float16)v.w };
            ((half4_t*)vh)[i - n4] = h;
        }
    }
}

// ---------------- main: LDS-staged gathers, DPP reduces ----------------
// One wave per query row. 8 groups of 8 lanes:
//   g  = lane>>3 : group g handles keys {4g..4g+3}
//   c8 = lane&7  : channels [8*c8, 8*c8+8)  (16 B of an fp16 row)
// Staging: 8 x global_load_lds dwordx4 put all 32 K rows + 32 V rows
// (8 KB) into this wave's LDS slice in ONE L2 round — in-flight data
// lives in the vmcnt queue, not VGPRs, sidestepping the allocator's
// serialization (R4/R8/R11: VGPR pinned at 28). Stage instr j writes
// key/val row (8j+g) at byte (8j+g)*128 (+ c8*16 per lane) — linear.
// Readback: each 8-lane group's ds_read_b128 covers one contiguous
// 128-B row -> conflict-free. No barrier: wave reads only its own slice.
// XCD pinning: group = bid&15 = (b*H+h); fp16 K+V per (b,h) = 1 MB,
// 2 groups/XCD -> 2 MB resident in that XCD's 4 MB L2.
__global__ __launch_bounds__(256) void topk_attn_f16(
    const float*    __restrict__ query,
    const _Float16* __restrict__ keyh,
    const _Float16* __restrict__ valh,
    const int*      __restrict__ pos,
    float*          __restrict__ out)
{
    __shared__ __align__(16) _Float16 sm[4][4096];  // per wave: 2048 K + 2048 V halves

    const int bid    = blockIdx.x;        // 0..16383
    const int group  = bid & 15;          // b*H + h
    const int lchunk = bid >> 4;          // 0..1023
    const int wave   = threadIdx.x >> 6;
    const int lane   = threadIdx.x & 63;
    const int g      = lane >> 3;         // 0..7
    const int c8     = lane & 7;          // 0..7

    const int b = group >> 3;
    const int h = group & 7;
    const int l = lchunk * 4 + wave;

    const size_t row  = ((size_t)(b * Lq + l) * H + h);
    const size_t qoff = row * (size_t)C;

    // pos for stage instr j: key (8j + g)
    int pj[4];
    #pragma unroll
    for (int j = 0; j < 4; ++j)
        pj[j] = pos[row * (size_t)K + 8 * j + g];

    const _Float16* kbase = keyh + (size_t)b * Lk * HC + (size_t)h * C;
    const _Float16* vbase = valh + (size_t)b * Lk * HC + (size_t)h * C;

    _Float16* smK = &sm[wave][0];
    _Float16* smV = &sm[wave][2048];

    // ---- issue all 8 staging gathers (one L2 round, zero VGPR cost) ----
    #pragma unroll
    for (int j = 0; j < 4; ++j)
        stage16(kbase + (size_t)pj[j] * HC + 8 * c8, smK + j * 512);
    #pragma unroll
    for (int j = 0; j < 4; ++j)
        stage16(vbase + (size_t)pj[j] * HC + 8 * c8, smV + j * 512);

    // q load + pack overlaps the staging latency
    const float4 qa = *(const float4*)(query + qoff + 8 * c8);
    const float4 qb = *(const float4*)(query + qoff + 8 * c8 + 4);
    h2 qp[4];
    qp[0] = pack_h2(qa.x * INV_SCALE, qa.y * INV_SCALE);
    qp[1] = pack_h2(qa.z * INV_SCALE, qa.w * INV_SCALE);
    qp[2] = pack_h2(qb.x * INV_SCALE, qb.y * INV_SCALE);
    qp[3] = pack_h2(qb.z * INV_SCALE, qb.w * INV_SCALE);

    // all staged data landed in LDS
    asm volatile("s_waitcnt vmcnt(0)" ::: "memory");

    // ---- scores from LDS: s[i] = score of key 4g+i ----
    const char* smKb = (const char*)smK;
    float s[4];
    #pragma unroll
    for (int i = 0; i < 4; ++i) {
        const int k = 4 * g + i;
        const uint4 kv = *(const uint4*)(smKb + k * 128 + c8 * 16);
        float t = fdot2(qp[0], __builtin_bit_cast(h2, kv.x), 0.0f);
        t = fdot2(qp[1], __builtin_bit_cast(h2, kv.y), t);
        t = fdot2(qp[2], __builtin_bit_cast(h2, kv.z), t);
        t = fdot2(qp[3], __builtin_bit_cast(h2, kv.w), t);
        t += dpp_f<0xB1>(t);     // xor1 (quad_perm)
        t += dpp_f<0x4E>(t);     // xor2 (quad_perm)
        t += dpp_f<0x141>(t);    // xor4 (row_half_mirror, valid after xor1+xor2)
        s[i] = t;
    }

    // ---- softmax over all 32 keys ----
    float mx = fmaxf(fmaxf(s[0], s[1]), fmaxf(s[2], s[3]));
    mx = fmaxf(mx, dpp_f<0x128>(mx));        // xor8 via ROW_ROR:8
    mx = fmaxf(mx, __shfl_xor(mx, 16));
    mx = fmaxf(mx, __shfl_xor(mx, 32));

    float se = 0.0f;
    #pragma unroll
    for (int i = 0; i < 4; ++i) { s[i] = __expf(s[i] - mx); se += s[i]; }
    se += dpp_f<0x128>(se);                  // xor8
    se += __shfl_xor(se, 16);
    se += __shfl_xor(se, 32);
    const float inv = 1.0f / se;

    // ---- PV from LDS: packed fp16 accumulate ----
    const char* smVb = (const char*)smV;
    h2 acc[4] = { h2{0,0}, h2{0,0}, h2{0,0}, h2{0,0} };
    #pragma unroll
    for (int i = 0; i < 4; ++i) {
        const int k = 4 * g + i;
        const uint4 vv = *(const uint4*)(smVb + k * 128 + c8 * 16);
        const float a = s[i] * inv;
        const h2 a2 = pack_h2(a, a);
        acc[0] = a2 * __builtin_bit_cast(h2, vv.x) + acc[0];
        acc[1] = a2 * __builtin_bit_cast(h2, vv.y) + acc[1];
        acc[2] = a2 * __builtin_bit_cast(h2, vv.z) + acc[2];
        acc[3] = a2 * __builtin_bit_cast(h2, vv.w) + acc[3];
    }
    // cross-group tree reduce: xor8 on VALU, xor16/32 via DS
    #pragma unroll
    for (int j = 0; j < 4; ++j) acc[j] = acc[j] + dpp_h2<0x128>(acc[j]);
    #pragma unroll
    for (int j = 0; j < 4; ++j) acc[j] = acc[j] + shfl_h2_xor(acc[j], 16);
    #pragma unroll
    for (int j = 0; j < 4; ++j) acc[j] = acc[j] + shfl_h2_xor(acc[j], 32);

    if (g == 0) {
        const float4 o0 = make_float4((float)acc[0].x, (float)acc[0].y,
                                      (float)acc[1].x, (float)acc[1].y);
        const float4 o1 = make_float4((float)acc[2].x, (float)acc[2].y,
                                      (float)acc[3].x, (float)acc[3].y);
        *(float4*)(out + qoff + 8 * c8)     = o0;
        *(float4*)(out + qoff + 8 * c8 + 4) = o1;
    }
}

// ---------------- fallback: proven R2 fp32 kernel (if ws too small) ----------
__global__ __launch_bounds__(256) void topk_attn_f32(
    const float* __restrict__ query,
    const float* __restrict__ key,
    const float* __restrict__ value,
    const int*   __restrict__ pos,
    float*       __restrict__ out)
{
    const int bid    = blockIdx.x;
    const int group  = bid & 15;
    const int lchunk = bid >> 4;
    const int wave   = threadIdx.x >> 6;
    const int lane   = threadIdx.x & 63;
    const int g      = lane >> 4;
    const int c4     = lane & 15;

    const int b = group >> 3;
    const int h = group & 7;
    const int l = lchunk * 4 + wave;

    const size_t row  = ((size_t)(b * Lq + l) * H + h);
    const size_t qoff = row * (size_t)C;

    float4 q4 = *(const float4*)(query + qoff + 4 * c4);
    q4.x *= INV_SCALE; q4.y *= INV_SCALE; q4.z *= INV_SCALE; q4.w *= INV_SCALE;

    const int p = pos[row * (size_t)K + (lane & 31)];

    const float* kbase = key   + (size_t)b * Lk * HC + (size_t)h * C;
    const float* vbase = value + (size_t)b * Lk * HC + (size_t)h * C;

    int off[8];
    #pragma unroll
    for (int i = 0; i < 8; ++i)
        off[i] = __shfl(p, 4 * i + g) * HC + 4 * c4;

    float s[8];
    #pragma unroll
    for (int i = 0; i < 8; ++i) {
        const float4 kv = *(const float4*)(kbase + off[i]);
        float t = q4.x * kv.x;
        t = fmaf(q4.y, kv.y, t);
        t = fmaf(q4.z, kv.z, t);
        t = fmaf(q4.w, kv.w, t);
        #pragma unroll
        for (int m = 8; m >= 1; m >>= 1) t += __shfl_xor(t, m);
        s[i] = t;
    }

    float mx = s[0];
    #pragma unroll
    for (int i = 1; i < 8; ++i) mx = fmaxf(mx, s[i]);
    mx = fmaxf(mx, __shfl_xor(mx, 16));
    mx = fmaxf(mx, __shfl_xor(mx, 32));

    float se = 0.0f;
    #pragma unroll
    for (int i = 0; i < 8; ++i) { s[i] = __expf(s[i] - mx); se += s[i]; }
    se += __shfl_xor(se, 16);
    se += __shfl_xor(se, 32);
    const float inv = 1.0f / se;

    float4 acc = make_float4(0.f, 0.f, 0.f, 0.f);
    #pragma unroll
    for (int i = 0; i < 8; ++i) {
        const float a = s[i] * inv;
        const float4 v4 = *(const float4*)(vbase + off[i]);
        acc.x = fmaf(a, v4.x, acc.x);
        acc.y = fmaf(a, v4.y, acc.y);
        acc.z = fmaf(a, v4.z, acc.z);
        acc.w = fmaf(a, v4.w, acc.w);
    }
    #pragma unroll
    for (int m = 16; m <= 32; m <<= 1) {
        acc.x += __shfl_xor(acc.x, m);
        acc.y += __shfl_xor(acc.y, m);
        acc.z += __shfl_xor(acc.z, m);
        acc.w += __shfl_xor(acc.w, m);
    }

    if (g == 0) *(float4*)(out + qoff + 4 * c4) = acc;
}

extern "C" void kernel_launch(void* const* d_in, const int* in_sizes, int n_in,
                              void* d_out, int out_size, void* d_ws, size_t ws_size,
                              hipStream_t stream) {
    const float* query = (const float*)d_in[0];
    const float* key   = (const float*)d_in[1];
    const float* value = (const float*)d_in[2];
    const int*   pos   = (const int*)d_in[3];
    float* out = (float*)d_out;

    const int total_rows = B * Lq * H;          // 65536
    const int blocks = total_rows / 4;          // 16384 (4 waves/block)

    const size_t need = (size_t)2 * NKV * sizeof(_Float16);  // 16.8 MB
    if (ws_size >= need && d_ws != nullptr) {
        _Float16* kh = (_Float16*)d_ws;
        _Float16* vh = kh + NKV;
        convert_kv_f16<<<2048, 256, 0, stream>>>(key, value, kh, vh);
        topk_attn_f16<<<blocks, 256, 0, stream>>>(query, kh, vh, pos, out);
    } else {
        topk_attn_f32<<<blocks, 256, 0, stream>>>(query, key, value, pos, out);
    }
}

// Round 13
// 48.938 us; speedup vs baseline: 1.1113x; 1.1113x over previous
//
#include <hip/hip_runtime.h>
#include <math.h>

// Problem constants (from reference setup_inputs)
constexpr int B  = 2;
constexpr int Lq = 4096;
constexpr int Lk = 4096;
constexpr int H  = 8;
constexpr int C  = 64;
constexpr int K  = 32;
constexpr float INV_SCALE = 0.125f;
constexpr int HC = H * C;                 // 512 elements: row stride in key/value
constexpr int NKV = B * Lk * H * C;       // 4,194,304 elements per array

typedef _Float16 h2 __attribute__((ext_vector_type(2)));
typedef _Float16 half4_t __attribute__((ext_vector_type(4)));

static __device__ __forceinline__ h2 pack_h2(float lo, float hi) {
    return __builtin_bit_cast(h2, __builtin_amdgcn_cvt_pkrtz(lo, hi));
}

#if __has_builtin(__builtin_amdgcn_fdot2)
static __device__ __forceinline__ float fdot2(h2 a, h2 b, float c) {
    return __builtin_amdgcn_fdot2(a, b, c, false);
}
#else
static __device__ __forceinline__ float fdot2(h2 a, h2 b, float c) {
    return c + (float)a.x * (float)b.x + (float)a.y * (float)b.y;
}
#endif

static __device__ __forceinline__ h2 shfl_h2_xor(h2 v, int m) {
    int i = __builtin_bit_cast(int, v);
    i = __shfl_xor(i, m);
    return __builtin_bit_cast(h2, i);
}

// ---- DPP cross-lane (VALU pipe, not DS) ----
// 0xB1 quad_perm xor1; 0x4E quad_perm xor2; 0x141 row_half_mirror (==xor4
// after xor1+xor2); 0x128 ROW_ROR:8 (==xor8 exactly).
template<int CTRL>
static __device__ __forceinline__ float dpp_f(float x) {
    return __builtin_bit_cast(float,
        __builtin_amdgcn_update_dpp(0, __builtin_bit_cast(int, x),
                                    CTRL, 0xF, 0xF, true));
}
template<int CTRL>
static __device__ __forceinline__ h2 dpp_h2(h2 x) {
    return __builtin_bit_cast(h2,
        __builtin_amdgcn_update_dpp(0, __builtin_bit_cast(int, x),
                                    CTRL, 0xF, 0xF, true));
}

// ---------------- prepass: fp32 K,V -> fp16 in d_ws (streamed) ----------------
__global__ __launch_bounds__(256) void convert_kv_f16(
    const float* __restrict__ key,
    const float* __restrict__ value,
    _Float16*    __restrict__ kh,
    _Float16*    __restrict__ vh)
{
    const int n4 = NKV / 4;               // float4 chunks per array
    for (int i = blockIdx.x * blockDim.x + threadIdx.x;
         i < 2 * n4; i += gridDim.x * blockDim.x) {
        if (i < n4) {
            const float4 v = ((const float4*)key)[i];
            half4_t h = { (_Float16)v.x, (_Float16)v.y, (_Float16)v.z, (_Float16)v.w };
            ((half4_t*)kh)[i] = h;
        } else {
            const float4 v = ((const float4*)value)[i - n4];
            half4_t h = { (_Float16)v.x, (_Float16)v.y, (_Float16)v.z, (_Float16)v.w };
            ((half4_t*)vh)[i - n4] = h;
        }
    }
}

// ---------------- main: persistent waves, R11 body per row ----------------
// 2048 blocks = 8 blocks/CU resident at launch (32 waves/CU = HW max),
// zero dispatch churn: each wave loops over 8 query rows of ITS (b,h)
// group. Fixes the dispatch-rate-limited ~55% occupancy of the 16384-
// short-block version; TLP (8 waves/SIMD x ~2 outstanding gathers) is
// the latency-hiding mechanism.
// Per row (R11 body): 8 groups of 8 lanes; group g handles keys 4g..4g+3;
// c8 = channel slot (16 B of the 128-B fp16 row). 4 K + 4 V register
// gathers; DPP reduces (xor1/2/4/8 on VALU); only xor16/32 via DS.
// XCD pinning: group = bid&15 = (b*H+h); fp16 K+V per (b,h) = 1 MB,
// 2 groups/XCD -> 2 MB resident in that XCD's 4 MB L2.
__global__ __launch_bounds__(256) void topk_attn_f16(
    const float*    __restrict__ query,
    const _Float16* __restrict__ keyh,
    const _Float16* __restrict__ valh,
    const int*      __restrict__ pos,
    float*          __restrict__ out)
{
    const int bid   = blockIdx.x;         // 0..2047
    const int group = bid & 15;           // b*H + h
    const int blkg  = bid >> 4;           // 0..127 within group
    const int wave  = threadIdx.x >> 6;
    const int lane  = threadIdx.x & 63;
    const int g     = lane >> 3;          // 0..7
    const int c8    = lane & 7;           // 0..7

    const int b = group >> 3;
    const int h = group & 7;

    const _Float16* kbase = keyh + (size_t)b * Lk * HC + (size_t)h * C;
    const _Float16* vbase = valh + (size_t)b * Lk * HC + (size_t)h * C;

    const int wslot = blkg * 4 + wave;    // 0..511 within group

    #pragma unroll 1
    for (int iter = 0; iter < 8; ++iter) {
        const int l = wslot + iter * 512;             // 0..4095

        const size_t row  = ((size_t)(b * Lq + l) * H + h);
        const size_t qoff = row * (size_t)C;

        // this group's 4 pos entries, loaded directly
        const int4 pq = *(const int4*)(pos + row * (size_t)K + 4 * g);

        int off[4];
        off[0] = pq.x * HC + 8 * c8;
        off[1] = pq.y * HC + 8 * c8;
        off[2] = pq.z * HC + 8 * c8;
        off[3] = pq.w * HC + 8 * c8;

        // ---- all 4 K rows + 4 V rows into registers ----
        uint4 kv[4], vv[4];
        #pragma unroll
        for (int i = 0; i < 4; ++i) kv[i] = *(const uint4*)(kbase + off[i]);
        #pragma unroll
        for (int i = 0; i < 4; ++i) vv[i] = *(const uint4*)(vbase + off[i]);

        // q channels [8c8, 8c8+8), pre-scaled, packed to 4x half2
        const float4 qa = *(const float4*)(query + qoff + 8 * c8);
        const float4 qb = *(const float4*)(query + qoff + 8 * c8 + 4);
        h2 qp[4];
        qp[0] = pack_h2(qa.x * INV_SCALE, qa.y * INV_SCALE);
        qp[1] = pack_h2(qa.z * INV_SCALE, qa.w * INV_SCALE);
        qp[2] = pack_h2(qb.x * INV_SCALE, qb.y * INV_SCALE);
        qp[3] = pack_h2(qb.z * INV_SCALE, qb.w * INV_SCALE);

        // ---- scores: s[i] = score of key 4g+i, replicated within group ----
        float s[4];
        #pragma unroll
        for (int i = 0; i < 4; ++i) {
            float t = fdot2(qp[0], __builtin_bit_cast(h2, kv[i].x), 0.0f);
            t = fdot2(qp[1], __builtin_bit_cast(h2, kv[i].y), t);
            t = fdot2(qp[2], __builtin_bit_cast(h2, kv[i].z), t);
            t = fdot2(qp[3], __builtin_bit_cast(h2, kv[i].w), t);
            t += dpp_f<0xB1>(t);     // xor1
            t += dpp_f<0x4E>(t);     // xor2
            t += dpp_f<0x141>(t);    // xor4
            s[i] = t;
        }

        // ---- softmax over all 32 keys ----
        float mx = fmaxf(fmaxf(s[0], s[1]), fmaxf(s[2], s[3]));
        mx = fmaxf(mx, dpp_f<0x128>(mx));        // xor8
        mx = fmaxf(mx, __shfl_xor(mx, 16));
        mx = fmaxf(mx, __shfl_xor(mx, 32));

        float se = 0.0f;
        #pragma unroll
        for (int i = 0; i < 4; ++i) { s[i] = __expf(s[i] - mx); se += s[i]; }
        se += dpp_f<0x128>(se);                  // xor8
        se += __shfl_xor(se, 16);
        se += __shfl_xor(se, 32);
        const float inv = 1.0f / se;

        // ---- PV: packed fp16 accumulate from registers ----
        h2 acc[4] = { h2{0,0}, h2{0,0}, h2{0,0}, h2{0,0} };
        #pragma unroll
        for (int i = 0; i < 4; ++i) {
            const float a = s[i] * inv;
            const h2 a2 = pack_h2(a, a);
            acc[0] = a2 * __builtin_bit_cast(h2, vv[i].x) + acc[0];
            acc[1] = a2 * __builtin_bit_cast(h2, vv[i].y) + acc[1];
            acc[2] = a2 * __builtin_bit_cast(h2, vv[i].z) + acc[2];
            acc[3] = a2 * __builtin_bit_cast(h2, vv[i].w) + acc[3];
        }
        // cross-group tree reduce: xor8 on VALU, xor16/32 via DS
        #pragma unroll
        for (int j = 0; j < 4; ++j) acc[j] = acc[j] + dpp_h2<0x128>(acc[j]);
        #pragma unroll
        for (int j = 0; j < 4; ++j) acc[j] = acc[j] + shfl_h2_xor(acc[j], 16);
        #pragma unroll
        for (int j = 0; j < 4; ++j) acc[j] = acc[j] + shfl_h2_xor(acc[j], 32);

        if (g == 0) {
            const float4 o0 = make_float4((float)acc[0].x, (float)acc[0].y,
                                          (float)acc[1].x, (float)acc[1].y);
            const float4 o1 = make_float4((float)acc[2].x, (float)acc[2].y,
                                          (float)acc[3].x, (float)acc[3].y);
            *(float4*)(out + qoff + 8 * c8)     = o0;
            *(float4*)(out + qoff + 8 * c8 + 4) = o1;
        }
    }
}

// ---------------- fallback: proven R2 fp32 kernel (if ws too small) ----------
__global__ __launch_bounds__(256) void topk_attn_f32(
    const float* __restrict__ query,
    const float* __restrict__ key,
    const float* __restrict__ value,
    const int*   __restrict__ pos,
    float*       __restrict__ out)
{
    const int bid    = blockIdx.x;
    const int group  = bid & 15;
    const int lchunk = bid >> 4;
    const int wave   = threadIdx.x >> 6;
    const int lane   = threadIdx.x & 63;
    const int g      = lane >> 4;
    const int c4     = lane & 15;

    const int b = group >> 3;
    const int h = group & 7;
    const int l = lchunk * 4 + wave;

    const size_t row  = ((size_t)(b * Lq + l) * H + h);
    const size_t qoff = row * (size_t)C;

    float4 q4 = *(const float4*)(query + qoff + 4 * c4);
    q4.x *= INV_SCALE; q4.y *= INV_SCALE; q4.z *= INV_SCALE; q4.w *= INV_SCALE;

    const int p = pos[row * (size_t)K + (lane & 31)];

    const float* kbase = key   + (size_t)b * Lk * HC + (size_t)h * C;
    const float* vbase = value + (size_t)b * Lk * HC + (size_t)h * C;

    int off[8];
    #pragma unroll
    for (int i = 0; i < 8; ++i)
        off[i] = __shfl(p, 4 * i + g) * HC + 4 * c4;

    float s[8];
    #pragma unroll
    for (int i = 0; i < 8; ++i) {
        const float4 kv = *(const float4*)(kbase + off[i]);
        float t = q4.x * kv.x;
        t = fmaf(q4.y, kv.y, t);
        t = fmaf(q4.z, kv.z, t);
        t = fmaf(q4.w, kv.w, t);
        #pragma unroll
        for (int m = 8; m >= 1; m >>= 1) t += __shfl_xor(t, m);
        s[i] = t;
    }

    float mx = s[0];
    #pragma unroll
    for (int i = 1; i < 8; ++i) mx = fmaxf(mx, s[i]);
    mx = fmaxf(mx, __shfl_xor(mx, 16));
    mx = fmaxf(mx, __shfl_xor(mx, 32));

    float se = 0.0f;
    #pragma unroll
    for (int i = 0; i < 8; ++i) { s[i] = __expf(s[i] - mx); se += s[i]; }
    se += __shfl_xor(se, 16);
    se += __shfl_xor(se, 32);
    const float inv = 1.0f / se;

    float4 acc = make_float4(0.f, 0.f, 0.f, 0.f);
    #pragma unroll
    for (int i = 0; i < 8; ++i) {
        const float a = s[i] * inv;
        const float4 v4 = *(const float4*)(vbase + off[i]);
        acc.x = fmaf(a, v4.x, acc.x);
        acc.y = fmaf(a, v4.y, acc.y);
        acc.z = fmaf(a, v4.z, acc.z);
        acc.w = fmaf(a, v4.w, acc.w);
    }
    #pragma unroll
    for (int m = 16; m <= 32; m <<= 1) {
        acc.x += __shfl_xor(acc.x, m);
        acc.y += __shfl_xor(acc.y, m);
        acc.z += __shfl_xor(acc.z, m);
        acc.w += __shfl_xor(acc.w, m);
    }

    if (g == 0) *(float4*)(out + qoff + 4 * c4) = acc;
}

extern "C" void kernel_launch(void* const* d_in, const int* in_sizes, int n_in,
                              void* d_out, int out_size, void* d_ws, size_t ws_size,
                              hipStream_t stream) {
    const float* query = (const float*)d_in[0];
    const float* key   = (const float*)d_in[1];
    const float* value = (const float*)d_in[2];
    const int*   pos   = (const int*)d_in[3];
    float* out = (float*)d_out;

    const size_t need = (size_t)2 * NKV * sizeof(_Float16);  // 16.8 MB
    if (ws_size >= need && d_ws != nullptr) {
        _Float16* kh = (_Float16*)d_ws;
        _Float16* vh = kh + NKV;
        convert_kv_f16<<<2048, 256, 0, stream>>>(key, value, kh, vh);
        // persistent grid: 2048 blocks x 4 waves x 8 rows = 65536 rows
        topk_attn_f16<<<2048, 256, 0, stream>>>(query, kh, vh, pos, out);
    } else {
        const int total_rows = B * Lq * H;      // 65536
        topk_attn_f32<<<total_rows / 4, 256, 0, stream>>>(query, key, value, pos, out);
    }
}

// Round 14
// 47.810 us; speedup vs baseline: 1.1376x; 1.0236x over previous
//
#include <hip/hip_runtime.h>
#include <math.h>

// Problem constants (from reference setup_inputs)
constexpr int B  = 2;
constexpr int Lq = 4096;
constexpr int Lk = 4096;
constexpr int H  = 8;
constexpr int C  = 64;
constexpr int K  = 32;
constexpr float INV_SCALE = 0.125f;
constexpr int HC = H * C;                 // 512 elements: row stride in key/value
constexpr int NKV = B * Lk * H * C;       // 4,194,304 elements per array

typedef _Float16 h2 __attribute__((ext_vector_type(2)));
typedef _Float16 half4_t __attribute__((ext_vector_type(4)));

static __device__ __forceinline__ h2 pack_h2(float lo, float hi) {
    return __builtin_bit_cast(h2, __builtin_amdgcn_cvt_pkrtz(lo, hi));
}

#if __has_builtin(__builtin_amdgcn_fdot2)
static __device__ __forceinline__ float fdot2(h2 a, h2 b, float c) {
    return __builtin_amdgcn_fdot2(a, b, c, false);
}
#else
static __device__ __forceinline__ float fdot2(h2 a, h2 b, float c) {
    return c + (float)a.x * (float)b.x + (float)a.y * (float)b.y;
}
#endif

static __device__ __forceinline__ h2 shfl_h2_xor(h2 v, int m) {
    int i = __builtin_bit_cast(int, v);
    i = __shfl_xor(i, m);
    return __builtin_bit_cast(h2, i);
}

// ---- DPP cross-lane (VALU pipe, not DS) ----
// 0xB1 quad_perm xor1; 0x4E quad_perm xor2; 0x141 row_half_mirror (==xor4
// after xor1+xor2); 0x128 ROW_ROR:8 (==xor8 exactly).
template<int CTRL>
static __device__ __forceinline__ float dpp_f(float x) {
    return __builtin_bit_cast(float,
        __builtin_amdgcn_update_dpp(0, __builtin_bit_cast(int, x),
                                    CTRL, 0xF, 0xF, true));
}
template<int CTRL>
static __device__ __forceinline__ h2 dpp_h2(h2 x) {
    return __builtin_bit_cast(h2,
        __builtin_amdgcn_update_dpp(0, __builtin_bit_cast(int, x),
                                    CTRL, 0xF, 0xF, true));
}

// volatile asm 16-B global load: issue order is GUARANTEED (volatile asm
// cannot be reordered against other volatile asm) -> 8 back-to-back issues
// = 8-deep MLP, immune to the allocator's serialization (R4/R8/R11,
// VGPR pinned at 28). Drained by one explicit vmcnt(0) below.
static __device__ __forceinline__ uint4 gload16(const _Float16* p) {
    uint4 r;
    asm volatile("global_load_dwordx4 %0, %1, off"
                 : "=v"(r) : "v"(p) : "memory");
    return r;
}

// ---------------- prepass: fp32 K,V -> fp16 in d_ws (streamed) ----------------
__global__ __launch_bounds__(256) void convert_kv_f16(
    const float* __restrict__ key,
    const float* __restrict__ value,
    _Float16*    __restrict__ kh,
    _Float16*    __restrict__ vh)
{
    const int n4 = NKV / 4;               // float4 chunks per array
    for (int i = blockIdx.x * blockDim.x + threadIdx.x;
         i < 2 * n4; i += gridDim.x * blockDim.x) {
        if (i < n4) {
            const float4 v = ((const float4*)key)[i];
            half4_t h = { (_Float16)v.x, (_Float16)v.y, (_Float16)v.z, (_Float16)v.w };
            ((half4_t*)kh)[i] = h;
        } else {
            const float4 v = ((const float4*)value)[i - n4];
            half4_t h = { (_Float16)v.x, (_Float16)v.y, (_Float16)v.z, (_Float16)v.w };
            ((half4_t*)vh)[i - n4] = h;
        }
    }
}

// ---------------- main: R11 body + forced 8-deep gather MLP ----------------
// One wave per query row. 8 groups of 8 lanes:
//   g  = lane>>3 : group g handles keys {4g..4g+3}
//   c8 = lane&7  : channels [8*c8, 8*c8+8)  (16 B of an fp16 row)
// Loads: pos int4 (auto) -> 8 volatile-asm gathers back-to-back (4 K + 4 V)
// -> q loads + pack (auto, overlaps gather latency) -> one vmcnt(0) +
// sched_barrier(0) (rule #18) -> all compute from registers.
// Reduces: xor1/2/4/8 on DPP (VALU); only xor16/32 via DS.
// XCD pinning: group = bid&15 = (b*H+h); fp16 K+V per (b,h) = 1 MB,
// 2 groups/XCD -> 2 MB resident in that XCD's 4 MB L2.
__global__ __launch_bounds__(256) void topk_attn_f16(
    const float*    __restrict__ query,
    const _Float16* __restrict__ keyh,
    const _Float16* __restrict__ valh,
    const int*      __restrict__ pos,
    float*          __restrict__ out)
{
    const int bid    = blockIdx.x;        // 0..16383
    const int group  = bid & 15;          // b*H + h
    const int lchunk = bid >> 4;          // 0..1023
    const int wave   = threadIdx.x >> 6;
    const int lane   = threadIdx.x & 63;
    const int g      = lane >> 3;         // 0..7
    const int c8     = lane & 7;          // 0..7

    const int b = group >> 3;
    const int h = group & 7;
    const int l = lchunk * 4 + wave;

    const size_t row  = ((size_t)(b * Lq + l) * H + h);
    const size_t qoff = row * (size_t)C;

    // this group's 4 pos entries (compiler-managed load + wait)
    const int4 pq = *(const int4*)(pos + row * (size_t)K + 4 * g);

    const _Float16* kbase = keyh + (size_t)b * Lk * HC + (size_t)h * C;
    const _Float16* vbase = valh + (size_t)b * Lk * HC + (size_t)h * C;

    int off[4];
    off[0] = pq.x * HC + 8 * c8;
    off[1] = pq.y * HC + 8 * c8;
    off[2] = pq.z * HC + 8 * c8;
    off[3] = pq.w * HC + 8 * c8;

    // ---- 8 gathers issued back-to-back (forced 8-deep MLP) ----
    uint4 kv[4], vv[4];
    #pragma unroll
    for (int i = 0; i < 4; ++i) kv[i] = gload16(kbase + off[i]);
    #pragma unroll
    for (int i = 0; i < 4; ++i) vv[i] = gload16(vbase + off[i]);

    // q load + pack overlaps the gathers' latency (compiler-managed)
    const float4 qa = *(const float4*)(query + qoff + 8 * c8);
    const float4 qb = *(const float4*)(query + qoff + 8 * c8 + 4);
    h2 qp[4];
    qp[0] = pack_h2(qa.x * INV_SCALE, qa.y * INV_SCALE);
    qp[1] = pack_h2(qa.z * INV_SCALE, qa.w * INV_SCALE);
    qp[2] = pack_h2(qb.x * INV_SCALE, qb.y * INV_SCALE);
    qp[3] = pack_h2(qb.z * INV_SCALE, qb.w * INV_SCALE);

    // drain the asm gathers; sched_barrier stops uses being hoisted above
    asm volatile("s_waitcnt vmcnt(0)" ::: "memory");
    __builtin_amdgcn_sched_barrier(0);

    // ---- scores: s[i] = score of key 4g+i, replicated within the group ----
    float s[4];
    #pragma unroll
    for (int i = 0; i < 4; ++i) {
        float t = fdot2(qp[0], __builtin_bit_cast(h2, kv[i].x), 0.0f);
        t = fdot2(qp[1], __builtin_bit_cast(h2, kv[i].y), t);
        t = fdot2(qp[2], __builtin_bit_cast(h2, kv[i].z), t);
        t = fdot2(qp[3], __builtin_bit_cast(h2, kv[i].w), t);
        t += dpp_f<0xB1>(t);     // xor1
        t += dpp_f<0x4E>(t);     // xor2
        t += dpp_f<0x141>(t);    // xor4
        s[i] = t;
    }

    // ---- softmax over all 32 keys ----
    float mx = fmaxf(fmaxf(s[0], s[1]), fmaxf(s[2], s[3]));
    mx = fmaxf(mx, dpp_f<0x128>(mx));        // xor8
    mx = fmaxf(mx, __shfl_xor(mx, 16));
    mx = fmaxf(mx, __shfl_xor(mx, 32));

    float se = 0.0f;
    #pragma unroll
    for (int i = 0; i < 4; ++i) { s[i] = __expf(s[i] - mx); se += s[i]; }
    se += dpp_f<0x128>(se);                  // xor8
    se += __shfl_xor(se, 16);
    se += __shfl_xor(se, 32);
    const float inv = 1.0f / se;

    // ---- PV: packed fp16 accumulate from registers ----
    h2 acc[4] = { h2{0,0}, h2{0,0}, h2{0,0}, h2{0,0} };
    #pragma unroll
    for (int i = 0; i < 4; ++i) {
        const float a = s[i] * inv;
        const h2 a2 = pack_h2(a, a);
        acc[0] = a2 * __builtin_bit_cast(h2, vv[i].x) + acc[0];
        acc[1] = a2 * __builtin_bit_cast(h2, vv[i].y) + acc[1];
        acc[2] = a2 * __builtin_bit_cast(h2, vv[i].z) + acc[2];
        acc[3] = a2 * __builtin_bit_cast(h2, vv[i].w) + acc[3];
    }
    // cross-group tree reduce: xor8 on VALU, xor16/32 via DS
    #pragma unroll
    for (int j = 0; j < 4; ++j) acc[j] = acc[j] + dpp_h2<0x128>(acc[j]);
    #pragma unroll
    for (int j = 0; j < 4; ++j) acc[j] = acc[j] + shfl_h2_xor(acc[j], 16);
    #pragma unroll
    for (int j = 0; j < 4; ++j) acc[j] = acc[j] + shfl_h2_xor(acc[j], 32);

    if (g == 0) {
        const float4 o0 = make_float4((float)acc[0].x, (float)acc[0].y,
                                      (float)acc[1].x, (float)acc[1].y);
        const float4 o1 = make_float4((float)acc[2].x, (float)acc[2].y,
                                      (float)acc[3].x, (float)acc[3].y);
        *(float4*)(out + qoff + 8 * c8)     = o0;
        *(float4*)(out + qoff + 8 * c8 + 4) = o1;
    }
}

// ---------------- fallback: proven R2 fp32 kernel (if ws too small) ----------
__global__ __launch_bounds__(256) void topk_attn_f32(
    const float* __restrict__ query,
    const float* __restrict__ key,
    const float* __restrict__ value,
    const int*   __restrict__ pos,
    float*       __restrict__ out)
{
    const int bid    = blockIdx.x;
    const int group  = bid & 15;
    const int lchunk = bid >> 4;
    const int wave   = threadIdx.x >> 6;
    const int lane   = threadIdx.x & 63;
    const int g      = lane >> 4;
    const int c4     = lane & 15;

    const int b = group >> 3;
    const int h = group & 7;
    const int l = lchunk * 4 + wave;

    const size_t row  = ((size_t)(b * Lq + l) * H + h);
    const size_t qoff = row * (size_t)C;

    float4 q4 = *(const float4*)(query + qoff + 4 * c4);
    q4.x *= INV_SCALE; q4.y *= INV_SCALE; q4.z *= INV_SCALE; q4.w *= INV_SCALE;

    const int p = pos[row * (size_t)K + (lane & 31)];

    const float* kbase = key   + (size_t)b * Lk * HC + (size_t)h * C;
    const float* vbase = value + (size_t)b * Lk * HC + (size_t)h * C;

    int off[8];
    #pragma unroll
    for (int i = 0; i < 8; ++i)
        off[i] = __shfl(p, 4 * i + g) * HC + 4 * c4;

    float s[8];
    #pragma unroll
    for (int i = 0; i < 8; ++i) {
        const float4 kv = *(const float4*)(kbase + off[i]);
        float t = q4.x * kv.x;
        t = fmaf(q4.y, kv.y, t);
        t = fmaf(q4.z, kv.z, t);
        t = fmaf(q4.w, kv.w, t);
        #pragma unroll
        for (int m = 8; m >= 1; m >>= 1) t += __shfl_xor(t, m);
        s[i] = t;
    }

    float mx = s[0];
    #pragma unroll
    for (int i = 1; i < 8; ++i) mx = fmaxf(mx, s[i]);
    mx = fmaxf(mx, __shfl_xor(mx, 16));
    mx = fmaxf(mx, __shfl_xor(mx, 32));

    float se = 0.0f;
    #pragma unroll
    for (int i = 0; i < 8; ++i) { s[i] = __expf(s[i] - mx); se += s[i]; }
    se += __shfl_xor(se, 16);
    se += __shfl_xor(se, 32);
    const float inv = 1.0f / se;

    float4 acc = make_float4(0.f, 0.f, 0.f, 0.f);
    #pragma unroll
    for (int i = 0; i < 8; ++i) {
        const float a = s[i] * inv;
        const float4 v4 = *(const float4*)(vbase + off[i]);
        acc.x = fmaf(a, v4.x, acc.x);
        acc.y = fmaf(a, v4.y, acc.y);
        acc.z = fmaf(a, v4.z, acc.z);
        acc.w = fmaf(a, v4.w, acc.w);
    }
    #pragma unroll
    for (int m = 16; m <= 32; m <<= 1) {
        acc.x += __shfl_xor(acc.x, m);
        acc.y += __shfl_xor(acc.y, m);
        acc.z += __shfl_xor(acc.z, m);
        acc.w += __shfl_xor(acc.w, m);
    }

    if (g == 0) *(float4*)(out + qoff + 4 * c4) = acc;
}

extern "C" void kernel_launch(void* const* d_in, const int* in_sizes, int n_in,
                              void* d_out, int out_size, void* d_ws, size_t ws_size,
                              hipStream_t stream) {
    const float* query = (const float*)d_in[0];
    const float* key   = (const float*)d_in[1];
    const float* value = (const float*)d_in[2];
    const int*   pos   = (const int*)d_in[3];
    float* out = (float*)d_out;

    const int total_rows = B * Lq * H;          // 65536
    const int blocks = total_rows / 4;          // 16384 (4 waves/block)

    const size_t need = (size_t)2 * NKV * sizeof(_Float16);  // 16.8 MB
    if (ws_size >= need && d_ws != nullptr) {
        _Float16* kh = (_Float16*)d_ws;
        _Float16* vh = kh + NKV;
        convert_kv_f16<<<2048, 256, 0, stream>>>(key, value, kh, vh);
        topk_attn_f16<<<blocks, 256, 0, stream>>>(query, kh, vh, pos, out);
    } else {
        topk_attn_f32<<<blocks, 256, 0, stream>>>(query, key, value, pos, out);
    }
}

// Round 15
// 45.742 us; speedup vs baseline: 1.1890x; 1.0452x over previous
//
#include <hip/hip_runtime.h>
#include <math.h>

// Problem constants (from reference setup_inputs)
constexpr int B  = 2;
constexpr int Lq = 4096;
constexpr int Lk = 4096;
constexpr int H  = 8;
constexpr int C  = 64;
constexpr int K  = 32;
constexpr float INV_SCALE = 0.125f;
constexpr int HC = H * C;                 // 512 elements: row stride in key/value
constexpr int NKV = B * Lk * H * C;       // 4,194,304 elements per array

typedef _Float16 h2 __attribute__((ext_vector_type(2)));
typedef _Float16 half4_t __attribute__((ext_vector_type(4)));

static __device__ __forceinline__ h2 pack_h2(float lo, float hi) {
    return __builtin_bit_cast(h2, __builtin_amdgcn_cvt_pkrtz(lo, hi));
}

#if __has_builtin(__builtin_amdgcn_fdot2)
static __device__ __forceinline__ float fdot2(h2 a, h2 b, float c) {
    return __builtin_amdgcn_fdot2(a, b, c, false);
}
#else
static __device__ __forceinline__ float fdot2(h2 a, h2 b, float c) {
    return c + (float)a.x * (float)b.x + (float)a.y * (float)b.y;
}
#endif

static __device__ __forceinline__ h2 shfl_h2_xor(h2 v, int m) {
    int i = __builtin_bit_cast(int, v);
    i = __shfl_xor(i, m);
    return __builtin_bit_cast(h2, i);
}

// ---- DPP cross-lane (VALU pipe, not DS) ----
// 0xB1 quad_perm xor1; 0x4E quad_perm xor2; 0x141 row_half_mirror (==xor4
// after xor1+xor2); 0x128 ROW_ROR:8 (==xor8 exactly).
template<int CTRL>
static __device__ __forceinline__ float dpp_f(float x) {
    return __builtin_bit_cast(float,
        __builtin_amdgcn_update_dpp(0, __builtin_bit_cast(int, x),
                                    CTRL, 0xF, 0xF, true));
}
template<int CTRL>
static __device__ __forceinline__ h2 dpp_h2(h2 x) {
    return __builtin_bit_cast(h2,
        __builtin_amdgcn_update_dpp(0, __builtin_bit_cast(int, x),
                                    CTRL, 0xF, 0xF, true));
}

// ---------------- prepass: fp32 K,V -> fp16 in d_ws (streamed) ----------------
__global__ __launch_bounds__(256) void convert_kv_f16(
    const float* __restrict__ key,
    const float* __restrict__ value,
    _Float16*    __restrict__ kh,
    _Float16*    __restrict__ vh)
{
    const int n4 = NKV / 4;               // float4 chunks per array
    for (int i = blockIdx.x * blockDim.x + threadIdx.x;
         i < 2 * n4; i += gridDim.x * blockDim.x) {
        if (i < n4) {
            const float4 v = ((const float4*)key)[i];
            half4_t h = { (_Float16)v.x, (_Float16)v.y, (_Float16)v.z, (_Float16)v.w };
            ((half4_t*)kh)[i] = h;
        } else {
            const float4 v = ((const float4*)value)[i - n4];
            half4_t h = { (_Float16)v.x, (_Float16)v.y, (_Float16)v.z, (_Float16)v.w };
            ((half4_t*)vh)[i - n4] = h;
        }
    }
}

// ---------------- main: R11 body + relaxed occupancy target ----------------
// One wave per query row. 8 groups of 8 lanes:
//   g  = lane>>3 : group g handles keys {4g..4g+3}
//   c8 = lane&7  : channels [8*c8, 8*c8+8)  (16 B of an fp16 row)
// __launch_bounds__(256, 2): min 2 waves/EU -> VGPR budget ~128/wave.
// R4/R8/R11/R14 all pinned at VGPR 24-36 (allocator targeting 8 waves/EU)
// and serialized the 8 gathers to stay there; this relaxes the pressure
// limit so the pre-RA scheduler's natural load clustering can keep all
// 4 K + 4 V gathers in flight (registers, no asm, no LDS).
// Reduces: xor1/2/4/8 on DPP (VALU); only xor16/32 via DS.
// XCD pinning: group = bid&15 = (b*H+h); fp16 K+V per (b,h) = 1 MB,
// 2 groups/XCD -> 2 MB resident in that XCD's 4 MB L2.
__global__ __launch_bounds__(256, 2) void topk_attn_f16(
    const float*    __restrict__ query,
    const _Float16* __restrict__ keyh,
    const _Float16* __restrict__ valh,
    const int*      __restrict__ pos,
    float*          __restrict__ out)
{
    const int bid    = blockIdx.x;        // 0..16383
    const int group  = bid & 15;          // b*H + h
    const int lchunk = bid >> 4;          // 0..1023
    const int wave   = threadIdx.x >> 6;
    const int lane   = threadIdx.x & 63;
    const int g      = lane >> 3;         // 0..7
    const int c8     = lane & 7;          // 0..7

    const int b = group >> 3;
    const int h = group & 7;
    const int l = lchunk * 4 + wave;

    const size_t row  = ((size_t)(b * Lq + l) * H + h);
    const size_t qoff = row * (size_t)C;

    // this group's 4 pos entries, loaded directly
    const int4 pq = *(const int4*)(pos + row * (size_t)K + 4 * g);

    const _Float16* kbase = keyh + (size_t)b * Lk * HC + (size_t)h * C;
    const _Float16* vbase = valh + (size_t)b * Lk * HC + (size_t)h * C;

    int off[4];
    off[0] = pq.x * HC + 8 * c8;
    off[1] = pq.y * HC + 8 * c8;
    off[2] = pq.z * HC + 8 * c8;
    off[3] = pq.w * HC + 8 * c8;

    // ---- all 4 K rows + 4 V rows into registers ----
    uint4 kv[4], vv[4];
    #pragma unroll
    for (int i = 0; i < 4; ++i) kv[i] = *(const uint4*)(kbase + off[i]);
    #pragma unroll
    for (int i = 0; i < 4; ++i) vv[i] = *(const uint4*)(vbase + off[i]);

    // q channels [8c8, 8c8+8), pre-scaled, packed to 4x half2
    const float4 qa = *(const float4*)(query + qoff + 8 * c8);
    const float4 qb = *(const float4*)(query + qoff + 8 * c8 + 4);
    h2 qp[4];
    qp[0] = pack_h2(qa.x * INV_SCALE, qa.y * INV_SCALE);
    qp[1] = pack_h2(qa.z * INV_SCALE, qa.w * INV_SCALE);
    qp[2] = pack_h2(qb.x * INV_SCALE, qb.y * INV_SCALE);
    qp[3] = pack_h2(qb.z * INV_SCALE, qb.w * INV_SCALE);

    // ---- scores: s[i] = score of key 4g+i, replicated within the group ----
    float s[4];
    #pragma unroll
    for (int i = 0; i < 4; ++i) {
        float t = fdot2(qp[0], __builtin_bit_cast(h2, kv[i].x), 0.0f);
        t = fdot2(qp[1], __builtin_bit_cast(h2, kv[i].y), t);
        t = fdot2(qp[2], __builtin_bit_cast(h2, kv[i].z), t);
        t = fdot2(qp[3], __builtin_bit_cast(h2, kv[i].w), t);
        t += dpp_f<0xB1>(t);     // xor1
        t += dpp_f<0x4E>(t);     // xor2
        t += dpp_f<0x141>(t);    // xor4
        s[i] = t;
    }

    // ---- softmax over all 32 keys ----
    float mx = fmaxf(fmaxf(s[0], s[1]), fmaxf(s[2], s[3]));
    mx = fmaxf(mx, dpp_f<0x128>(mx));        // xor8
    mx = fmaxf(mx, __shfl_xor(mx, 16));
    mx = fmaxf(mx, __shfl_xor(mx, 32));

    float se = 0.0f;
    #pragma unroll
    for (int i = 0; i < 4; ++i) { s[i] = __expf(s[i] - mx); se += s[i]; }
    se += dpp_f<0x128>(se);                  // xor8
    se += __shfl_xor(se, 16);
    se += __shfl_xor(se, 32);
    const float inv = 1.0f / se;

    // ---- PV: packed fp16 accumulate from registers ----
    h2 acc[4] = { h2{0,0}, h2{0,0}, h2{0,0}, h2{0,0} };
    #pragma unroll
    for (int i = 0; i < 4; ++i) {
        const float a = s[i] * inv;
        const h2 a2 = pack_h2(a, a);
        acc[0] = a2 * __builtin_bit_cast(h2, vv[i].x) + acc[0];
        acc[1] = a2 * __builtin_bit_cast(h2, vv[i].y) + acc[1];
        acc[2] = a2 * __builtin_bit_cast(h2, vv[i].z) + acc[2];
        acc[3] = a2 * __builtin_bit_cast(h2, vv[i].w) + acc[3];
    }
    // cross-group tree reduce: xor8 on VALU, xor16/32 via DS
    #pragma unroll
    for (int j = 0; j < 4; ++j) acc[j] = acc[j] + dpp_h2<0x128>(acc[j]);
    #pragma unroll
    for (int j = 0; j < 4; ++j) acc[j] = acc[j] + shfl_h2_xor(acc[j], 16);
    #pragma unroll
    for (int j = 0; j < 4; ++j) acc[j] = acc[j] + shfl_h2_xor(acc[j], 32);

    if (g == 0) {
        const float4 o0 = make_float4((float)acc[0].x, (float)acc[0].y,
                                      (float)acc[1].x, (float)acc[1].y);
        const float4 o1 = make_float4((float)acc[2].x, (float)acc[2].y,
                                      (float)acc[3].x, (float)acc[3].y);
        *(float4*)(out + qoff + 8 * c8)     = o0;
        *(float4*)(out + qoff + 8 * c8 + 4) = o1;
    }
}

// ---------------- fallback: proven R2 fp32 kernel (if ws too small) ----------
__global__ __launch_bounds__(256) void topk_attn_f32(
    const float* __restrict__ query,
    const float* __restrict__ key,
    const float* __restrict__ value,
    const int*   __restrict__ pos,
    float*       __restrict__ out)
{
    const int bid    = blockIdx.x;
    const int group  = bid & 15;
    const int lchunk = bid >> 4;
    const int wave   = threadIdx.x >> 6;
    const int lane   = threadIdx.x & 63;
    const int g      = lane >> 4;
    const int c4     = lane & 15;

    const int b = group >> 3;
    const int h = group & 7;
    const int l = lchunk * 4 + wave;

    const size_t row  = ((size_t)(b * Lq + l) * H + h);
    const size_t qoff = row * (size_t)C;

    float4 q4 = *(const float4*)(query + qoff + 4 * c4);
    q4.x *= INV_SCALE; q4.y *= INV_SCALE; q4.z *= INV_SCALE; q4.w *= INV_SCALE;

    const int p = pos[row * (size_t)K + (lane & 31)];

    const float* kbase = key   + (size_t)b * Lk * HC + (size_t)h * C;
    const float* vbase = value + (size_t)b * Lk * HC + (size_t)h * C;

    int off[8];
    #pragma unroll
    for (int i = 0; i < 8; ++i)
        off[i] = __shfl(p, 4 * i + g) * HC + 4 * c4;

    float s[8];
    #pragma unroll
    for (int i = 0; i < 8; ++i) {
        const float4 kv = *(const float4*)(kbase + off[i]);
        float t = q4.x * kv.x;
        t = fmaf(q4.y, kv.y, t);
        t = fmaf(q4.z, kv.z, t);
        t = fmaf(q4.w, kv.w, t);
        #pragma unroll
        for (int m = 8; m >= 1; m >>= 1) t += __shfl_xor(t, m);
        s[i] = t;
    }

    float mx = s[0];
    #pragma unroll
    for (int i = 1; i < 8; ++i) mx = fmaxf(mx, s[i]);
    mx = fmaxf(mx, __shfl_xor(mx, 16));
    mx = fmaxf(mx, __shfl_xor(mx, 32));

    float se = 0.0f;
    #pragma unroll
    for (int i = 0; i < 8; ++i) { s[i] = __expf(s[i] - mx); se += s[i]; }
    se += __shfl_xor(se, 16);
    se += __shfl_xor(se, 32);
    const float inv = 1.0f / se;

    float4 acc = make_float4(0.f, 0.f, 0.f, 0.f);
    #pragma unroll
    for (int i = 0; i < 8; ++i) {
        const float a = s[i] * inv;
        const float4 v4 = *(const float4*)(vbase + off[i]);
        acc.x = fmaf(a, v4.x, acc.x);
        acc.y = fmaf(a, v4.y, acc.y);
        acc.z = fmaf(a, v4.z, acc.z);
        acc.w = fmaf(a, v4.w, acc.w);
    }
    #pragma unroll
    for (int m = 16; m <= 32; m <<= 1) {
        acc.x += __shfl_xor(acc.x, m);
        acc.y += __shfl_xor(acc.y, m);
        acc.z += __shfl_xor(acc.z, m);
        acc.w += __shfl_xor(acc.w, m);
    }

    if (g == 0) *(float4*)(out + qoff + 4 * c4) = acc;
}

extern "C" void kernel_launch(void* const* d_in, const int* in_sizes, int n_in,
                              void* d_out, int out_size, void* d_ws, size_t ws_size,
                              hipStream_t stream) {
    const float* query = (const float*)d_in[0];
    const float* key   = (const float*)d_in[1];
    const float* value = (const float*)d_in[2];
    const int*   pos   = (const int*)d_in[3];
    float* out = (float*)d_out;

    const int total_rows = B * Lq * H;          // 65536
    const int blocks = total_rows / 4;          // 16384 (4 waves/block)

    const size_t need = (size_t)2 * NKV * sizeof(_Float16);  // 16.8 MB
    if (ws_size >= need && d_ws != nullptr) {
        _Float16* kh = (_Float16*)d_ws;
        _Float16* vh = kh + NKV;
        convert_kv_f16<<<2048, 256, 0, stream>>>(key, value, kh, vh);
        topk_attn_f16<<<blocks, 256, 0, stream>>>(query, kh, vh, pos, out);
    } else {
        topk_attn_f32<<<blocks, 256, 0, stream>>>(query, key, value, pos, out);
    }
}